// Round 8
// baseline (80.497 us; speedup 1.0000x reference)
//
#include <hip/hip_runtime.h>
#include <stdint.h>

// ---------------------------------------------------------------------------
// Fast math helpers.
// ---------------------------------------------------------------------------
__device__ __forceinline__ float fast_exp(float x) {
  return __builtin_amdgcn_exp2f(x * 1.4426950408889634f);
}
__device__ __forceinline__ float fast_rcp(float x) {
  return __builtin_amdgcn_rcpf(x);
}
__device__ __forceinline__ float fast_cos(float x) {
  // v_cos takes revolutions; v_fract does the range reduction.
  return __builtin_amdgcn_cosf(__builtin_amdgcn_fractf(x * 0.15915494309189535f));
}
__device__ __forceinline__ float fast_sigmoid(float x) {
  return fast_rcp(1.0f + fast_exp(-x));
}
__device__ __forceinline__ float fast_tanh(float x) {
  return 1.0f - 2.0f * fast_rcp(1.0f + fast_exp(2.0f * x));
}
// sigmoid on [-1,1]: 0.5 + x/4 - x^3/48 + x^5/480 - 17x^7/80640 (err ~2e-5)
__device__ __forceinline__ float sigmoid_poly(float x) {
  float x2 = x * x;
  float p = fmaf(fmaf(fmaf(-2.1085373e-4f, x2, 2.0833334e-3f), x2,
                      -2.0833334e-2f), x2, 0.25f);
  return fmaf(x, p, 0.5f);
}
// tanh Pade(5,4): err <1e-6 @|x|<=1, <1.3e-4 @|x|<=2.5 (cell state bound ~2.1)
__device__ __forceinline__ float tanh_pade(float x) {
  float x2 = x * x;
  float num = x * fmaf(x2 + 105.f, x2, 945.f);
  float den = fmaf(fmaf(15.f, x2, 420.f), x2, 945.f);
  return num * fast_rcp(den);
}

// Cross-lane XOR exchange within each 4-lane quad via DPP quad_perm
// (update_dpp, tied-old operand — verified correct R7; ~4cy VALU).
template <int CTRL>
__device__ __forceinline__ float dppf(float v) {
  return __int_as_float(__builtin_amdgcn_update_dpp(
      0, __float_as_int(v), CTRL, 0xf, 0xf, true));
}
#define QP_XOR1 0xB1  // [1,0,3,2]
#define QP_XOR2 0x4E  // [2,3,0,1]
#define QP_XOR3 0x1B  // [3,2,1,0]

// Direct global->LDS DMA (16B/lane). LDS dest is wave-uniform base + lane*16
// (linear, m104); swizzling is done on the per-lane GLOBAL source address
// (m173 pattern). AS casts via uintptr_t = CK-production pattern.
__device__ __forceinline__ void gload_lds16(const float* gp, const float* lp) {
  __builtin_amdgcn_global_load_lds(
      reinterpret_cast<const uint32_t __attribute__((address_space(1)))*>(
          reinterpret_cast<uintptr_t>(gp)),
      reinterpret_cast<uint32_t __attribute__((address_space(3)))*>(
          reinterpret_cast<uintptr_t>(lp)),
      16, 0, 0);
}

// ---------------------------------------------------------------------------
// Kernel 1: precompute x-part of gate activations.
//   Z[t][j][b][g] = x[t,b,:] . W_g[row_j, :D] + fold   (j in {0,1,2} -> linear
// rows {0,1,3}; row 2 is dead: RZ on |0> is a global phase). fold = bias+theta
// for rows 0,3.
// Structure (evidence-driven):
//  - 1-wave workgroups, global_load_lds direct DMA (no VGPR round trip, no
//    register state across phases -> no R4-style spill), NO barriers at all:
//    pipeline with counted s_waitcnt vmcnt(8)/(0) over a 2x8KB LDS dbuf.
//  - LDS written linearly by DMA; bank-conflict-free reads via pre-swizzled
//    global source: content[row][c4] = x[row][c4 ^ (row&7)], read back with
//    the same XOR -> each 8-lane group covers all 32 banks.
// ---------------------------------------------------------------------------
__global__ __launch_bounds__(64) void qlstm_gemm(
    const float* __restrict__ x,
    const float* __restrict__ Wf, const float* __restrict__ bf,
    const float* __restrict__ Wi, const float* __restrict__ bi,
    const float* __restrict__ Wu, const float* __restrict__ bu,
    const float* __restrict__ Wo, const float* __restrict__ bo,
    const float* __restrict__ thf, const float* __restrict__ thi,
    const float* __restrict__ thu, const float* __restrict__ tho,
    float* __restrict__ Z, long long rows, int B, int D)
{
  __shared__ float buf[2][64][32];  // 16 KB double buffer
  const long long base = (long long)blockIdx.x * 64;
  const int tid = threadIdx.x;  // 0..63
  const long long r = base + tid;
  const bool valid = r < rows;
  const int ldw = D + 4;
  const float* Ws[4] = {Wf, Wi, Wu, Wo};
  const float* bs[4] = {bf, bi, bu, bo};
  const float* ts[4] = {thf, thi, thu, tho};

  const int lgrp = tid >> 3;                 // 0..7 (row-within-8 group)
  const int lcol = tid & 7;                  // dest float4 column
  const int scol4 = lcol ^ lgrp;             // swizzled SOURCE float4 column

  float acc[12];
#pragma unroll
  for (int g = 0; g < 4; ++g) {
    acc[g * 3 + 0] = bs[g][0] + ts[g][0];  // theta0 folded
    acc[g * 3 + 1] = bs[g][1];
    acc[g * 3 + 2] = bs[g][3] + ts[g][3];  // theta3 folded
  }

  const int nkc = D >> 5;  // D multiple of 32 (D=128)

  // issue 8 DMA instructions staging 64 rows x 32 cols of chunk kc into buf[w]
  auto issue = [&](int kc, int w) {
#pragma unroll
    for (int i = 0; i < 8; ++i) {
      long long gr = base + i * 8 + lgrp;
      if (gr >= rows) gr = rows - 1;  // clamp (rows%64==0 in practice)
      const float* gp = x + gr * (long long)D + kc * 32 + scol4 * 4;
      gload_lds16(gp, &buf[w][i * 8][0]);  // dest: base + lane*16 (linear)
    }
  };

  issue(0, 0);
  if (nkc > 1) issue(1, 1);

  for (int kc = 0; kc < nkc; ++kc) {
    if (kc + 2 < nkc) {
      asm volatile("s_waitcnt vmcnt(8)" ::: "memory");  // buf[kc&1] ready
      // note: next issue targets buf[kc&1] only at kc+2; reads below finish
      // hundreds of cycles before that DMA could land.
    } else {
      asm volatile("s_waitcnt vmcnt(0)" ::: "memory");
    }
    if (valid) {
      const float(*tb)[32] = buf[kc & 1];
#pragma unroll
      for (int k4 = 0; k4 < 8; ++k4) {
        float4 xv = *(const float4*)&tb[tid][(k4 ^ lcol) * 4];
        int k = k4 * 4;
#pragma unroll
        for (int g = 0; g < 4; ++g) {
#pragma unroll
          for (int jj = 0; jj < 3; ++jj) {
            int row2 = (jj == 2) ? 3 : jj;
            const float* wp = Ws[g] + row2 * ldw + kc * 32 + k;  // uniform -> s_load
            acc[g * 3 + jj] += xv.x * wp[0] + xv.y * wp[1] + xv.z * wp[2] + xv.w * wp[3];
          }
        }
      }
    }
    if (kc + 2 < nkc) issue(kc + 2, kc & 1);
  }

  if (valid) {
    long long t = r / B;
    int b = (int)(r - t * B);
    float4 s0 = make_float4(acc[0], acc[3], acc[6], acc[9]);   // a0 per gate
    float4 s1 = make_float4(acc[1], acc[4], acc[7], acc[10]);  // a1 per gate
    float4 s2 = make_float4(acc[2], acc[5], acc[8], acc[11]);  // a3 per gate
    *(float4*)(Z + ((t * 3 + 0) * (long long)B + b) * 4) = s0;
    *(float4*)(Z + ((t * 3 + 1) * (long long)B + b) * 4) = s1;
    *(float4*)(Z + ((t * 3 + 2) * (long long)B + b) * 4) = s2;
  }
}

// ---------------------------------------------------------------------------
// Kernel 2: scan with 4 lanes per batch element (lane q = gate q; after the
// 4x4 quad transpose lane q = component q). Cross-lane via DPP quad_perm.
// Depth-8 named prefetch: Z is freshly written (cross-XCD L3 ~400-500cy);
// depth-4 x ~130cy chain barely covered it.
// ---------------------------------------------------------------------------
__global__ __launch_bounds__(64) void qlstm_scan4(
    const float* __restrict__ Z,
    const float* __restrict__ Wf, const float* __restrict__ Wi,
    const float* __restrict__ Wu, const float* __restrict__ Wo,
    const float* __restrict__ thf, const float* __restrict__ thi,
    const float* __restrict__ thu, const float* __restrict__ tho,
    float* __restrict__ out, int T, int B, int D)
{
  const int gid = blockIdx.x * 64 + threadIdx.x;
  const int b = gid >> 2, q = gid & 3;
  if (b >= B) return;

  const float* Wg = (q == 0) ? Wf : (q == 1) ? Wi : (q == 2) ? Wu : Wo;
  const float* th = (q == 0) ? thf : (q == 1) ? thi : (q == 2) ? thu : tho;
  const int ldw = D + 4;
  const float ct1 = fast_cos(th[1]);  // cos(theta1) of this lane's gate
  const float m2c = fast_cos(th[2]);  // cos(theta2) of this lane's gate

  // wh[jj][d] pairs with h from lane q^d (component q^d): XOR-permuted load.
  float wh[3][4];
#pragma unroll
  for (int jj = 0; jj < 3; ++jj) {
    int row = (jj == 2) ? 3 : jj;
#pragma unroll
    for (int d = 0; d < 4; ++d)
      wh[jj][d] = Wg[row * ldw + D + (q ^ d)];
  }
  const bool e0 = ((q & 1) == 0);
  const bool e1 = ((q & 2) == 0);

  float h = 0.f, c = 0.f;  // this lane holds component q of h and c

  const float* Zg = Z + gid;
  const size_t tstr = (size_t)12 * B;  // floats per time step
  const size_t pstr = (size_t)4 * B;   // floats per j-plane
  float* hx  = out + (size_t)T * B * 4;
  float* cxp = hx + (size_t)B * 4;

  auto ld3 = [&](int t, float& z0, float& z1, float& z2) {
    const float* p = Zg + (size_t)t * tstr;
    z0 = p[0]; z1 = p[pstr]; z2 = p[2 * pstr];
  };

  auto step = [&](float z0, float z1, float z2, int t) {
    // gather all 4 h components (h from lane q^d)
    float h1 = dppf<QP_XOR1>(h);
    float h2 = dppf<QP_XOR2>(h);
    float h3 = dppf<QP_XOR3>(h);
    float a0 = fmaf(wh[0][0], h, fmaf(wh[0][1], h1, fmaf(wh[0][2], h2, fmaf(wh[0][3], h3, z0))));
    float a1 = fmaf(wh[1][0], h, fmaf(wh[1][1], h1, fmaf(wh[1][2], h2, fmaf(wh[1][3], h3, z1))));
    float a2 = fmaf(wh[2][0], h, fmaf(wh[2][1], h1, fmaf(wh[2][2], h2, fmaf(wh[2][3], h3, z2))));
    // this lane's gate: wire measurements
    float m0 = fast_cos(a0);
    float m1 = ct1 * fast_cos(a1);
    float m3 = fast_cos(a2);
    float m01 = m0 * m1, m23 = m2c * m3;
    float g0 = m1 * m23;        // <Z0> = m1 m2 m3
    float g1 = m01;             // <Z1> = m0 m1
    float g2 = m01 * m2c;       // <Z2> = m0 m1 m2
    float g3 = m01 * m23;       // <Z3> = m0 m1 m2 m3
    // 4x4 quad transpose (two XOR stages); after: w_r = gate r's component q.
    float x0 = dppf<QP_XOR1>(g0);
    float x1 = dppf<QP_XOR1>(g1);
    float x2 = dppf<QP_XOR1>(g2);
    float x3 = dppf<QP_XOR1>(g3);
    float s0 = e0 ? g0 : x1;
    float s1 = e0 ? x0 : g1;
    float s2 = e0 ? g2 : x3;
    float s3 = e0 ? x2 : g3;
    float y0 = dppf<QP_XOR2>(s0);
    float y1 = dppf<QP_XOR2>(s1);
    float y2 = dppf<QP_XOR2>(s2);
    float y3 = dppf<QP_XOR2>(s3);
    float wf_ = e1 ? s0 : y2;
    float wi_ = e1 ? s1 : y3;
    float wu_ = e1 ? y0 : s2;
    float wo_ = e1 ? y1 : s3;
    // gates (|input| <= 1: products of cosines)
    float fg = sigmoid_poly(wf_);
    float ig = sigmoid_poly(wi_);
    float ug = tanh_pade(wu_);
    float og = sigmoid_poly(wo_);
    c = fmaf(fg, c, ig * ug);
    h = og * tanh_pade(c);
    out[(size_t)t * pstr + gid] = h;
  };

  // depth-8 named prefetch pipeline (rule #20: no runtime-indexed arrays)
  float A0, A1, A2, B0, B1, B2, C0, C1, C2, D0, D1, D2;
  float E0, E1, E2, F0, F1, F2, G0, G1, G2, H0, H1, H2;
  if (T > 0) ld3(0, A0, A1, A2);
  if (T > 1) ld3(1, B0, B1, B2);
  if (T > 2) ld3(2, C0, C1, C2);
  if (T > 3) ld3(3, D0, D1, D2);
  if (T > 4) ld3(4, E0, E1, E2);
  if (T > 5) ld3(5, F0, F1, F2);
  if (T > 6) ld3(6, G0, G1, G2);
  if (T > 7) ld3(7, H0, H1, H2);

  int T8 = T & ~7;
  for (int t = 0; t < T8; t += 8) {
    { float z0 = A0, z1 = A1, z2 = A2;
      if (t + 8 < T) ld3(t + 8, A0, A1, A2);
      step(z0, z1, z2, t); }
    { float z0 = B0, z1 = B1, z2 = B2;
      if (t + 9 < T) ld3(t + 9, B0, B1, B2);
      step(z0, z1, z2, t + 1); }
    { float z0 = C0, z1 = C1, z2 = C2;
      if (t + 10 < T) ld3(t + 10, C0, C1, C2);
      step(z0, z1, z2, t + 2); }
    { float z0 = D0, z1 = D1, z2 = D2;
      if (t + 11 < T) ld3(t + 11, D0, D1, D2);
      step(z0, z1, z2, t + 3); }
    { float z0 = E0, z1 = E1, z2 = E2;
      if (t + 12 < T) ld3(t + 12, E0, E1, E2);
      step(z0, z1, z2, t + 4); }
    { float z0 = F0, z1 = F1, z2 = F2;
      if (t + 13 < T) ld3(t + 13, F0, F1, F2);
      step(z0, z1, z2, t + 5); }
    { float z0 = G0, z1 = G1, z2 = G2;
      if (t + 14 < T) ld3(t + 14, G0, G1, G2);
      step(z0, z1, z2, t + 6); }
    { float z0 = H0, z1 = H1, z2 = H2;
      if (t + 15 < T) ld3(t + 15, H0, H1, H2);
      step(z0, z1, z2, t + 7); }
  }
  for (int t = T8; t < T; ++t) {
    float z0, z1, z2;
    ld3(t, z0, z1, z2);
    step(z0, z1, z2, t);
  }
  hx[gid]  = h;
  cxp[gid] = c;
}

// ---------------------------------------------------------------------------
// Fallback (only if workspace can't hold Z): fused, slow but correct.
// ---------------------------------------------------------------------------
struct GK {
  float wh[4][3][4];
  float ct1[4];
  float m2c[4];
};

__device__ __forceinline__ void load_gk(GK& K,
    const float* Wf, const float* Wi, const float* Wu, const float* Wo,
    const float* thf, const float* thi, const float* thu, const float* tho,
    int D)
{
  const float* Ws[4] = {Wf, Wi, Wu, Wo};
  const float* ts[4] = {thf, thi, thu, tho};
  const int ldw = D + 4;
#pragma unroll
  for (int g = 0; g < 4; ++g) {
#pragma unroll
    for (int jj = 0; jj < 3; ++jj) {
      int row = (jj == 2) ? 3 : jj;
#pragma unroll
      for (int qq = 0; qq < 4; ++qq)
        K.wh[g][jj][qq] = Ws[g][row * ldw + D + qq];
    }
    K.ct1[g] = fast_cos(ts[g][1]);
    K.m2c[g] = fast_cos(ts[g][2]);
  }
}

__device__ __forceinline__ void qlstm_step_sc(const float a[12], const GK& K,
                                              float h[4], float c[4])
{
  float gv[4][4];
#pragma unroll
  for (int g = 0; g < 4; ++g) {
    float m0 = fast_cos(a[g * 3 + 0]);
    float m1 = K.ct1[g] * fast_cos(a[g * 3 + 1]);
    float m3 = fast_cos(a[g * 3 + 2]);
    float m01 = m0 * m1;
    float m23 = K.m2c[g] * m3;
    gv[g][0] = m1 * m23;
    gv[g][1] = m01;
    gv[g][2] = m01 * K.m2c[g];
    gv[g][3] = m01 * m23;
  }
#pragma unroll
  for (int qq = 0; qq < 4; ++qq) {
    float fg = fast_sigmoid(gv[0][qq]);
    float ig = fast_sigmoid(gv[1][qq]);
    float ug = fast_tanh(gv[2][qq]);
    float og = fast_sigmoid(gv[3][qq]);
    c[qq] = fg * c[qq] + ig * ug;
    h[qq] = og * fast_tanh(c[qq]);
  }
}

__global__ __launch_bounds__(256) void qlstm_fused(
    const float* __restrict__ x,
    const float* __restrict__ Wf, const float* __restrict__ bf,
    const float* __restrict__ Wi, const float* __restrict__ bi,
    const float* __restrict__ Wu, const float* __restrict__ bu,
    const float* __restrict__ Wo, const float* __restrict__ bo,
    const float* __restrict__ thf, const float* __restrict__ thi,
    const float* __restrict__ thu, const float* __restrict__ tho,
    float* __restrict__ out, int T, int B, int D)
{
  int b = blockIdx.x * 256 + threadIdx.x;
  if (b >= B) return;
  GK K;
  load_gk(K, Wf, Wi, Wu, Wo, thf, thi, thu, tho, D);
  const float* Ws[4] = {Wf, Wi, Wu, Wo};
  const float* bs[4] = {bf, bi, bu, bo};
  const float* ts[4] = {thf, thi, thu, tho};
  const int ldw = D + 4;

  float base[12];
#pragma unroll
  for (int g = 0; g < 4; ++g) {
    base[g * 3 + 0] = bs[g][0] + ts[g][0];
    base[g * 3 + 1] = bs[g][1];
    base[g * 3 + 2] = bs[g][3] + ts[g][3];
  }

  float h[4] = {0.f, 0.f, 0.f, 0.f};
  float c[4] = {0.f, 0.f, 0.f, 0.f};
  float* hx  = out + (size_t)T * B * 4;
  float* cxp = hx + (size_t)B * 4;

  for (int t = 0; t < T; ++t) {
    float a[12];
#pragma unroll
    for (int j = 0; j < 12; ++j) a[j] = base[j];
    const float* xp = x + ((size_t)t * B + b) * D;
    for (int k = 0; k < D; k += 4) {
      float4 xv = *(const float4*)(xp + k);
#pragma unroll
      for (int g = 0; g < 4; ++g) {
        const float* W = Ws[g];
#pragma unroll
        for (int jj = 0; jj < 3; ++jj) {
          int row = (jj == 2) ? 3 : jj;
          const float* wp = W + row * ldw + k;
          a[g * 3 + jj] += xv.x * wp[0] + xv.y * wp[1] + xv.z * wp[2] + xv.w * wp[3];
        }
      }
    }
#pragma unroll
    for (int g = 0; g < 4; ++g) {
#pragma unroll
      for (int jj = 0; jj < 3; ++jj) {
        a[g * 3 + jj] += K.wh[g][jj][0] * h[0] + K.wh[g][jj][1] * h[1]
                       + K.wh[g][jj][2] * h[2] + K.wh[g][jj][3] * h[3];
      }
    }
    qlstm_step_sc(a, K, h, c);
    *(float4*)(out + ((size_t)t * B + b) * 4) = make_float4(h[0], h[1], h[2], h[3]);
  }
  *(float4*)(hx + (size_t)b * 4)  = make_float4(h[0], h[1], h[2], h[3]);
  *(float4*)(cxp + (size_t)b * 4) = make_float4(c[0], c[1], c[2], c[3]);
}

// ---------------------------------------------------------------------------
extern "C" void kernel_launch(void* const* d_in, const int* in_sizes, int n_in,
                              void* d_out, int out_size, void* d_ws, size_t ws_size,
                              hipStream_t stream)
{
  const float* x   = (const float*)d_in[0];
  const float* Wf  = (const float*)d_in[1];
  const float* bf  = (const float*)d_in[2];
  const float* Wi  = (const float*)d_in[3];
  const float* bi  = (const float*)d_in[4];
  const float* Wu  = (const float*)d_in[5];
  const float* bu  = (const float*)d_in[6];
  const float* Wo  = (const float*)d_in[7];
  const float* bo  = (const float*)d_in[8];
  const float* thf = (const float*)d_in[9];
  const float* thi = (const float*)d_in[10];
  const float* thu = (const float*)d_in[11];
  const float* tho = (const float*)d_in[12];

  int DH = in_sizes[1] / 4;                 // D + H (H = 4)
  int D  = DH - 4;                          // 128
  long long TB = (long long)in_sizes[0] / D;          // T*B
  int B = (int)(((long long)out_size - 4 * TB) / 8);  // out = 4*T*B + 8*B
  int T = (int)(TB / B);

  size_t zbytes = (size_t)TB * 12 * sizeof(float);
  if (ws_size >= zbytes && (D & 31) == 0) {
    float* Z = (float*)d_ws;
    int gblocks = (int)((TB + 63) / 64);
    qlstm_gemm<<<gblocks, 64, 0, stream>>>(x, Wf, bf, Wi, bi, Wu, bu, Wo, bo,
                                           thf, thi, thu, tho, Z, TB, B, D);
    int sthreads = B * 4;
    qlstm_scan4<<<(sthreads + 63) / 64, 64, 0, stream>>>(Z, Wf, Wi, Wu, Wo,
                                                         thf, thi, thu, tho,
                                                         (float*)d_out, T, B, D);
  } else {
    qlstm_fused<<<(B + 255) / 256, 256, 0, stream>>>(x, Wf, bf, Wi, bi, Wu, bu, Wo, bo,
                                                     thf, thi, thu, tho,
                                                     (float*)d_out, T, B, D);
  }
}

// Round 9
// 71.983 us; speedup vs baseline: 1.1183x; 1.1183x over previous
//
#include <hip/hip_runtime.h>
#include <stdint.h>

using f32x2 = __attribute__((ext_vector_type(2))) float;

// ---------------------------------------------------------------------------
// Fast math helpers.
// ---------------------------------------------------------------------------
__device__ __forceinline__ float fast_exp(float x) {
  return __builtin_amdgcn_exp2f(x * 1.4426950408889634f);
}
__device__ __forceinline__ float fast_rcp(float x) {
  return __builtin_amdgcn_rcpf(x);
}
__device__ __forceinline__ float fast_cos(float x) {
  // v_cos takes revolutions; v_fract does the range reduction.
  return __builtin_amdgcn_cosf(__builtin_amdgcn_fractf(x * 0.15915494309189535f));
}
__device__ __forceinline__ float fast_sigmoid(float x) {
  return fast_rcp(1.0f + fast_exp(-x));
}
__device__ __forceinline__ float fast_tanh(float x) {
  return 1.0f - 2.0f * fast_rcp(1.0f + fast_exp(2.0f * x));
}
// sigmoid on [-1,1]: 0.5 + x/4 - x^3/48 + x^5/480 - 17x^7/80640 (err ~2e-5)
__device__ __forceinline__ float sigmoid_poly(float x) {
  float x2 = x * x;
  float p = fmaf(fmaf(fmaf(-2.1085373e-4f, x2, 2.0833334e-3f), x2,
                      -2.0833334e-2f), x2, 0.25f);
  return fmaf(x, p, 0.5f);
}
// tanh Pade(5,4): err <1e-6 @|x|<=1, <1.3e-4 @|x|<=2.5 (cell state bound ~2.1)
__device__ __forceinline__ float tanh_pade(float x) {
  float x2 = x * x;
  float num = x * fmaf(x2 + 105.f, x2, 945.f);
  float den = fmaf(fmaf(15.f, x2, 420.f), x2, 945.f);
  return num * fast_rcp(den);
}

// Cross-lane XOR exchange within each 4-lane quad via DPP quad_perm
// (update_dpp, tied-old operand — verified correct R7; ~4cy VALU).
template <int CTRL>
__device__ __forceinline__ float dppf(float v) {
  return __int_as_float(__builtin_amdgcn_update_dpp(
      0, __float_as_int(v), CTRL, 0xf, 0xf, true));
}
#define QP_XOR1 0xB1  // [1,0,3,2]
#define QP_XOR2 0x4E  // [2,3,0,1]
#define QP_XOR3 0x1B  // [3,2,1,0]

// Packed 2xFP32 FMA (CDNA v_pk_fma_f32): acc += x * w, elementwise on pairs.
// w is wave-uniform (SGPR pair = 1 scalar operand, legal); x/acc are VGPR
// pairs. Halves the gemm's FMA instruction count (VALU floor 20.5 -> ~10us).
__device__ __forceinline__ void pk_fma(f32x2& acc, f32x2 x, f32x2 w) {
  asm("v_pk_fma_f32 %0, %1, %2, %0" : "+v"(acc) : "v"(x), "s"(w));
}

// ---------------------------------------------------------------------------
// Kernel 1: precompute x-part of gate activations.
//   Z[t][j][b][g] = x[t,b,:] . W_g[row_j, :D] + fold   (j in {0,1,2} -> linear
// rows {0,1,3}; row 2 is dead: RZ on |0> is a global phase). fold = bias+theta
// for rows 0,3.
// Structure (evidence-driven):
//  - 1-wave workgroups (R6: independent waves desync -> overlap staging).
//  - padded [64][36] tile (144B row stride = 9x16B): 0 bank conflicts
//    (R8's linear [64][32] DMA tile measured 524K conflicts -> reverted).
//  - loads feed ds_write immediately (R4: hoisted prefetch spilled to scratch).
//  - pk-FMA inner loop: VALU-issue floor was ~20.5us at scalar FMA; packed
//    halves instruction count.
// ---------------------------------------------------------------------------
__global__ __launch_bounds__(64) void qlstm_gemm(
    const float* __restrict__ x,
    const float* __restrict__ Wf, const float* __restrict__ bf,
    const float* __restrict__ Wi, const float* __restrict__ bi,
    const float* __restrict__ Wu, const float* __restrict__ bu,
    const float* __restrict__ Wo, const float* __restrict__ bo,
    const float* __restrict__ thf, const float* __restrict__ thi,
    const float* __restrict__ thu, const float* __restrict__ tho,
    float* __restrict__ Z, long long rows, int B, int D)
{
  __shared__ float tile[64][36];
  const long long base = (long long)blockIdx.x * 64;
  const int tid = threadIdx.x;  // 0..63
  const long long r = base + tid;
  const bool valid = r < rows;
  const int ldw = D + 4;
  const float* Ws[4] = {Wf, Wi, Wu, Wo};
  const float* bs[4] = {bf, bi, bu, bo};
  const float* ts[4] = {thf, thi, thu, tho};

  f32x2 acc[12];  // packed partial sums (even-k, odd-k); reduced at epilogue
#pragma unroll
  for (int g = 0; g < 4; ++g) {
    acc[g * 3 + 0] = f32x2{bs[g][0] + ts[g][0], 0.f};  // theta0 folded
    acc[g * 3 + 1] = f32x2{bs[g][1], 0.f};
    acc[g * 3 + 2] = f32x2{bs[g][3] + ts[g][3], 0.f};  // theta3 folded
  }

  const int nkc = D >> 5;  // D multiple of 32 (D=128)
  for (int kc = 0; kc < nkc; ++kc) {
    // stage 64 rows x 32 cols, coalesced (8 rows of 128B per instruction)
#pragma unroll
    for (int i = 0; i < 8; ++i) {
      int f = i * 64 + tid;
      int row = f >> 3, col = (f & 7) * 4;
      long long gr = base + row;
      if (gr < rows) {
        float4 v = *(const float4*)(x + gr * (long long)D + kc * 32 + col);
        *(float4*)&tile[row][col] = v;
      }
    }
    __syncthreads();  // 1-wave workgroup: near-free
    if (valid) {
#pragma unroll
      for (int k4 = 0; k4 < 8; ++k4) {
        float4 xv = *(float4*)&tile[tid][k4 * 4];
        f32x2 xlo = {xv.x, xv.y}, xhi = {xv.z, xv.w};
#pragma unroll
        for (int g = 0; g < 4; ++g) {
#pragma unroll
          for (int jj = 0; jj < 3; ++jj) {
            int row2 = (jj == 2) ? 3 : jj;
            // uniform address -> s_load_dwordx4 (SGPR quad, aligned pairs)
            const float* wp = Ws[g] + row2 * ldw + kc * 32 + k4 * 4;
            float4 wv = *(const float4*)wp;
            pk_fma(acc[g * 3 + jj], xlo, f32x2{wv.x, wv.y});
            pk_fma(acc[g * 3 + jj], xhi, f32x2{wv.z, wv.w});
          }
        }
      }
    }
    __syncthreads();
  }

  if (valid) {
    float a[12];
#pragma unroll
    for (int j = 0; j < 12; ++j) a[j] = acc[j].x + acc[j].y;
    long long t = r / B;
    int b = (int)(r - t * B);
    float4 s0 = make_float4(a[0], a[3], a[6], a[9]);   // a0 per gate
    float4 s1 = make_float4(a[1], a[4], a[7], a[10]);  // a1 per gate
    float4 s2 = make_float4(a[2], a[5], a[8], a[11]);  // a3 per gate
    *(float4*)(Z + ((t * 3 + 0) * (long long)B + b) * 4) = s0;
    *(float4*)(Z + ((t * 3 + 1) * (long long)B + b) * 4) = s1;
    *(float4*)(Z + ((t * 3 + 2) * (long long)B + b) * 4) = s2;
  }
}

// ---------------------------------------------------------------------------
// Kernel 2: scan with 4 lanes per batch element (lane q = gate q; after the
// 4x4 quad transpose lane q = component q). Cross-lane via DPP quad_perm.
// Depth-8 named prefetch (Z is freshly written, cross-XCD latency).
// ---------------------------------------------------------------------------
__global__ __launch_bounds__(64) void qlstm_scan4(
    const float* __restrict__ Z,
    const float* __restrict__ Wf, const float* __restrict__ Wi,
    const float* __restrict__ Wu, const float* __restrict__ Wo,
    const float* __restrict__ thf, const float* __restrict__ thi,
    const float* __restrict__ thu, const float* __restrict__ tho,
    float* __restrict__ out, int T, int B, int D)
{
  const int gid = blockIdx.x * 64 + threadIdx.x;
  const int b = gid >> 2, q = gid & 3;
  if (b >= B) return;

  const float* Wg = (q == 0) ? Wf : (q == 1) ? Wi : (q == 2) ? Wu : Wo;
  const float* th = (q == 0) ? thf : (q == 1) ? thi : (q == 2) ? thu : tho;
  const int ldw = D + 4;
  const float ct1 = fast_cos(th[1]);  // cos(theta1) of this lane's gate
  const float m2c = fast_cos(th[2]);  // cos(theta2) of this lane's gate

  // wh[jj][d] pairs with h from lane q^d (component q^d): XOR-permuted load.
  float wh[3][4];
#pragma unroll
  for (int jj = 0; jj < 3; ++jj) {
    int row = (jj == 2) ? 3 : jj;
#pragma unroll
    for (int d = 0; d < 4; ++d)
      wh[jj][d] = Wg[row * ldw + D + (q ^ d)];
  }
  const bool e0 = ((q & 1) == 0);
  const bool e1 = ((q & 2) == 0);

  float h = 0.f, c = 0.f;  // this lane holds component q of h and c

  const float* Zg = Z + gid;
  const size_t tstr = (size_t)12 * B;  // floats per time step
  const size_t pstr = (size_t)4 * B;   // floats per j-plane
  float* hx  = out + (size_t)T * B * 4;
  float* cxp = hx + (size_t)B * 4;

  auto ld3 = [&](int t, float& z0, float& z1, float& z2) {
    const float* p = Zg + (size_t)t * tstr;
    z0 = p[0]; z1 = p[pstr]; z2 = p[2 * pstr];
  };

  auto step = [&](float z0, float z1, float z2, int t) {
    // gather all 4 h components (h from lane q^d)
    float h1 = dppf<QP_XOR1>(h);
    float h2 = dppf<QP_XOR2>(h);
    float h3 = dppf<QP_XOR3>(h);
    float a0 = fmaf(wh[0][0], h, fmaf(wh[0][1], h1, fmaf(wh[0][2], h2, fmaf(wh[0][3], h3, z0))));
    float a1 = fmaf(wh[1][0], h, fmaf(wh[1][1], h1, fmaf(wh[1][2], h2, fmaf(wh[1][3], h3, z1))));
    float a2 = fmaf(wh[2][0], h, fmaf(wh[2][1], h1, fmaf(wh[2][2], h2, fmaf(wh[2][3], h3, z2))));
    // this lane's gate: wire measurements
    float m0 = fast_cos(a0);
    float m1 = ct1 * fast_cos(a1);
    float m3 = fast_cos(a2);
    float m01 = m0 * m1, m23 = m2c * m3;
    float g0 = m1 * m23;        // <Z0> = m1 m2 m3
    float g1 = m01;             // <Z1> = m0 m1
    float g2 = m01 * m2c;       // <Z2> = m0 m1 m2
    float g3 = m01 * m23;       // <Z3> = m0 m1 m2 m3
    // 4x4 quad transpose (two XOR stages); after: w_r = gate r's component q.
    float x0 = dppf<QP_XOR1>(g0);
    float x1 = dppf<QP_XOR1>(g1);
    float x2 = dppf<QP_XOR1>(g2);
    float x3 = dppf<QP_XOR1>(g3);
    float s0 = e0 ? g0 : x1;
    float s1 = e0 ? x0 : g1;
    float s2 = e0 ? g2 : x3;
    float s3 = e0 ? x2 : g3;
    float y0 = dppf<QP_XOR2>(s0);
    float y1 = dppf<QP_XOR2>(s1);
    float y2 = dppf<QP_XOR2>(s2);
    float y3 = dppf<QP_XOR2>(s3);
    float wf_ = e1 ? s0 : y2;
    float wi_ = e1 ? s1 : y3;
    float wu_ = e1 ? y0 : s2;
    float wo_ = e1 ? y1 : s3;
    // gates (|input| <= 1: products of cosines)
    float fg = sigmoid_poly(wf_);
    float ig = sigmoid_poly(wi_);
    float ug = tanh_pade(wu_);
    float og = sigmoid_poly(wo_);
    c = fmaf(fg, c, ig * ug);
    h = og * tanh_pade(c);
    out[(size_t)t * pstr + gid] = h;
  };

  // depth-8 named prefetch pipeline (rule #20: no runtime-indexed arrays)
  float A0, A1, A2, B0, B1, B2, C0, C1, C2, D0, D1, D2;
  float E0, E1, E2, F0, F1, F2, G0, G1, G2, H0, H1, H2;
  if (T > 0) ld3(0, A0, A1, A2);
  if (T > 1) ld3(1, B0, B1, B2);
  if (T > 2) ld3(2, C0, C1, C2);
  if (T > 3) ld3(3, D0, D1, D2);
  if (T > 4) ld3(4, E0, E1, E2);
  if (T > 5) ld3(5, F0, F1, F2);
  if (T > 6) ld3(6, G0, G1, G2);
  if (T > 7) ld3(7, H0, H1, H2);

  int T8 = T & ~7;
  for (int t = 0; t < T8; t += 8) {
    { float z0 = A0, z1 = A1, z2 = A2;
      if (t + 8 < T) ld3(t + 8, A0, A1, A2);
      step(z0, z1, z2, t); }
    { float z0 = B0, z1 = B1, z2 = B2;
      if (t + 9 < T) ld3(t + 9, B0, B1, B2);
      step(z0, z1, z2, t + 1); }
    { float z0 = C0, z1 = C1, z2 = C2;
      if (t + 10 < T) ld3(t + 10, C0, C1, C2);
      step(z0, z1, z2, t + 2); }
    { float z0 = D0, z1 = D1, z2 = D2;
      if (t + 11 < T) ld3(t + 11, D0, D1, D2);
      step(z0, z1, z2, t + 3); }
    { float z0 = E0, z1 = E1, z2 = E2;
      if (t + 12 < T) ld3(t + 12, E0, E1, E2);
      step(z0, z1, z2, t + 4); }
    { float z0 = F0, z1 = F1, z2 = F2;
      if (t + 13 < T) ld3(t + 13, F0, F1, F2);
      step(z0, z1, z2, t + 5); }
    { float z0 = G0, z1 = G1, z2 = G2;
      if (t + 14 < T) ld3(t + 14, G0, G1, G2);
      step(z0, z1, z2, t + 6); }
    { float z0 = H0, z1 = H1, z2 = H2;
      if (t + 15 < T) ld3(t + 15, H0, H1, H2);
      step(z0, z1, z2, t + 7); }
  }
  for (int t = T8; t < T; ++t) {
    float z0, z1, z2;
    ld3(t, z0, z1, z2);
    step(z0, z1, z2, t);
  }
  hx[gid]  = h;
  cxp[gid] = c;
}

// ---------------------------------------------------------------------------
// Fallback (only if workspace can't hold Z): fused, slow but correct.
// ---------------------------------------------------------------------------
struct GK {
  float wh[4][3][4];
  float ct1[4];
  float m2c[4];
};

__device__ __forceinline__ void load_gk(GK& K,
    const float* Wf, const float* Wi, const float* Wu, const float* Wo,
    const float* thf, const float* thi, const float* thu, const float* tho,
    int D)
{
  const float* Ws[4] = {Wf, Wi, Wu, Wo};
  const float* ts[4] = {thf, thi, thu, tho};
  const int ldw = D + 4;
#pragma unroll
  for (int g = 0; g < 4; ++g) {
#pragma unroll
    for (int jj = 0; jj < 3; ++jj) {
      int row = (jj == 2) ? 3 : jj;
#pragma unroll
      for (int qq = 0; qq < 4; ++qq)
        K.wh[g][jj][qq] = Ws[g][row * ldw + D + qq];
    }
    K.ct1[g] = fast_cos(ts[g][1]);
    K.m2c[g] = fast_cos(ts[g][2]);
  }
}

__device__ __forceinline__ void qlstm_step_sc(const float a[12], const GK& K,
                                              float h[4], float c[4])
{
  float gv[4][4];
#pragma unroll
  for (int g = 0; g < 4; ++g) {
    float m0 = fast_cos(a[g * 3 + 0]);
    float m1 = K.ct1[g] * fast_cos(a[g * 3 + 1]);
    float m3 = fast_cos(a[g * 3 + 2]);
    float m01 = m0 * m1;
    float m23 = K.m2c[g] * m3;
    gv[g][0] = m1 * m23;
    gv[g][1] = m01;
    gv[g][2] = m01 * K.m2c[g];
    gv[g][3] = m01 * m23;
  }
#pragma unroll
  for (int qq = 0; qq < 4; ++qq) {
    float fg = fast_sigmoid(gv[0][qq]);
    float ig = fast_sigmoid(gv[1][qq]);
    float ug = fast_tanh(gv[2][qq]);
    float og = fast_sigmoid(gv[3][qq]);
    c[qq] = fg * c[qq] + ig * ug;
    h[qq] = og * fast_tanh(c[qq]);
  }
}

__global__ __launch_bounds__(256) void qlstm_fused(
    const float* __restrict__ x,
    const float* __restrict__ Wf, const float* __restrict__ bf,
    const float* __restrict__ Wi, const float* __restrict__ bi,
    const float* __restrict__ Wu, const float* __restrict__ bu,
    const float* __restrict__ Wo, const float* __restrict__ bo,
    const float* __restrict__ thf, const float* __restrict__ thi,
    const float* __restrict__ thu, const float* __restrict__ tho,
    float* __restrict__ out, int T, int B, int D)
{
  int b = blockIdx.x * 256 + threadIdx.x;
  if (b >= B) return;
  GK K;
  load_gk(K, Wf, Wi, Wu, Wo, thf, thi, thu, tho, D);
  const float* Ws[4] = {Wf, Wi, Wu, Wo};
  const float* bs[4] = {bf, bi, bu, bo};
  const float* ts[4] = {thf, thi, thu, tho};
  const int ldw = D + 4;

  float base[12];
#pragma unroll
  for (int g = 0; g < 4; ++g) {
    base[g * 3 + 0] = bs[g][0] + ts[g][0];
    base[g * 3 + 1] = bs[g][1];
    base[g * 3 + 2] = bs[g][3] + ts[g][3];
  }

  float h[4] = {0.f, 0.f, 0.f, 0.f};
  float c[4] = {0.f, 0.f, 0.f, 0.f};
  float* hx  = out + (size_t)T * B * 4;
  float* cxp = hx + (size_t)B * 4;

  for (int t = 0; t < T; ++t) {
    float a[12];
#pragma unroll
    for (int j = 0; j < 12; ++j) a[j] = base[j];
    const float* xp = x + ((size_t)t * B + b) * D;
    for (int k = 0; k < D; k += 4) {
      float4 xv = *(const float4*)(xp + k);
#pragma unroll
      for (int g = 0; g < 4; ++g) {
        const float* W = Ws[g];
#pragma unroll
        for (int jj = 0; jj < 3; ++jj) {
          int row = (jj == 2) ? 3 : jj;
          const float* wp = W + row * ldw + k;
          a[g * 3 + jj] += xv.x * wp[0] + xv.y * wp[1] + xv.z * wp[2] + xv.w * wp[3];
        }
      }
    }
#pragma unroll
    for (int g = 0; g < 4; ++g) {
#pragma unroll
      for (int jj = 0; jj < 3; ++jj) {
        a[g * 3 + jj] += K.wh[g][jj][0] * h[0] + K.wh[g][jj][1] * h[1]
                       + K.wh[g][jj][2] * h[2] + K.wh[g][jj][3] * h[3];
      }
    }
    qlstm_step_sc(a, K, h, c);
    *(float4*)(out + ((size_t)t * B + b) * 4) = make_float4(h[0], h[1], h[2], h[3]);
  }
  *(float4*)(hx + (size_t)b * 4)  = make_float4(h[0], h[1], h[2], h[3]);
  *(float4*)(cxp + (size_t)b * 4) = make_float4(c[0], c[1], c[2], c[3]);
}

// ---------------------------------------------------------------------------
extern "C" void kernel_launch(void* const* d_in, const int* in_sizes, int n_in,
                              void* d_out, int out_size, void* d_ws, size_t ws_size,
                              hipStream_t stream)
{
  const float* x   = (const float*)d_in[0];
  const float* Wf  = (const float*)d_in[1];
  const float* bf  = (const float*)d_in[2];
  const float* Wi  = (const float*)d_in[3];
  const float* bi  = (const float*)d_in[4];
  const float* Wu  = (const float*)d_in[5];
  const float* bu  = (const float*)d_in[6];
  const float* Wo  = (const float*)d_in[7];
  const float* bo  = (const float*)d_in[8];
  const float* thf = (const float*)d_in[9];
  const float* thi = (const float*)d_in[10];
  const float* thu = (const float*)d_in[11];
  const float* tho = (const float*)d_in[12];

  int DH = in_sizes[1] / 4;                 // D + H (H = 4)
  int D  = DH - 4;                          // 128
  long long TB = (long long)in_sizes[0] / D;          // T*B
  int B = (int)(((long long)out_size - 4 * TB) / 8);  // out = 4*T*B + 8*B
  int T = (int)(TB / B);

  size_t zbytes = (size_t)TB * 12 * sizeof(float);
  if (ws_size >= zbytes && (D & 31) == 0) {
    float* Z = (float*)d_ws;
    int gblocks = (int)((TB + 63) / 64);
    qlstm_gemm<<<gblocks, 64, 0, stream>>>(x, Wf, bf, Wi, bi, Wu, bu, Wo, bo,
                                           thf, thi, thu, tho, Z, TB, B, D);
    int sthreads = B * 4;
    qlstm_scan4<<<(sthreads + 63) / 64, 64, 0, stream>>>(Z, Wf, Wi, Wu, Wo,
                                                         thf, thi, thu, tho,
                                                         (float*)d_out, T, B, D);
  } else {
    qlstm_fused<<<(B + 255) / 256, 256, 0, stream>>>(x, Wf, bf, Wi, bi, Wu, bu, Wo, bo,
                                                     thf, thi, thu, tho,
                                                     (float*)d_out, T, B, D);
  }
}

// Round 10
// 70.504 us; speedup vs baseline: 1.1417x; 1.0210x over previous
//
#include <hip/hip_runtime.h>
#include <stdint.h>

// ---------------------------------------------------------------------------
// Fast math helpers.
// ---------------------------------------------------------------------------
__device__ __forceinline__ float fast_exp(float x) {
  return __builtin_amdgcn_exp2f(x * 1.4426950408889634f);
}
__device__ __forceinline__ float fast_rcp(float x) {
  return __builtin_amdgcn_rcpf(x);
}
__device__ __forceinline__ float fast_cos(float x) {
  // v_cos takes revolutions; v_fract does the range reduction.
  return __builtin_amdgcn_cosf(__builtin_amdgcn_fractf(x * 0.15915494309189535f));
}
__device__ __forceinline__ float fast_sigmoid(float x) {
  return fast_rcp(1.0f + fast_exp(-x));
}
__device__ __forceinline__ float fast_tanh(float x) {
  return 1.0f - 2.0f * fast_rcp(1.0f + fast_exp(2.0f * x));
}
// sigmoid on [-1,1]: 0.5 + x/4 - x^3/48 + x^5/480 - 17x^7/80640 (err ~2e-5)
__device__ __forceinline__ float sigmoid_poly(float x) {
  float x2 = x * x;
  float p = fmaf(fmaf(fmaf(-2.1085373e-4f, x2, 2.0833334e-3f), x2,
                      -2.0833334e-2f), x2, 0.25f);
  return fmaf(x, p, 0.5f);
}
// tanh Pade(5,4): err <1e-6 @|x|<=1, <1.3e-4 @|x|<=2.5 (cell state bound ~2.1)
__device__ __forceinline__ float tanh_pade(float x) {
  float x2 = x * x;
  float num = x * fmaf(x2 + 105.f, x2, 945.f);
  float den = fmaf(fmaf(15.f, x2, 420.f), x2, 945.f);
  return num * fast_rcp(den);
}

// Cross-lane XOR exchange within each 4-lane quad via DPP quad_perm
// (update_dpp, tied-old operand — verified correct R7; ~4cy VALU).
template <int CTRL>
__device__ __forceinline__ float dppf(float v) {
  return __int_as_float(__builtin_amdgcn_update_dpp(
      0, __float_as_int(v), CTRL, 0xf, 0xf, true));
}
#define QP_XOR1 0xB1  // [1,0,3,2]
#define QP_XOR2 0x4E  // [2,3,0,1]
#define QP_XOR3 0x1B  // [3,2,1,0]

// ---------------------------------------------------------------------------
// Kernel 1: precompute x-part of gate activations.
//   Z layout: [t][b][gate][4]  (j=0,1,2 = wire0/wire1/wire3 angle, pad)
//   value = x[t,b,:] . W_g[row_j, :D] + fold  (linear rows {0,1,3}; row 2 is
//   dead: RZ on |0> is a global phase). fold = bias+theta for rows 0,3.
// Structure (evidence-driven):
//  - 1-wave workgroups (R6), padded [64][36] LDS tile: 0 bank conflicts
//    (R8's linear DMA tile: 524K conflicts -> global_load_lds ruled out).
//  - loads feed ds_write immediately (R4: hoisted prefetch spilled to scratch).
//  - scalar FMA inner loop (R9: pk-FMA regressed — kernel is latency-bound,
//    VALUBusy 8-13%, so halving VALU ops bought nothing and hurt scheduling).
//  - Z padded to 16 floats/(t,b) so the scan reads ONE aligned float4 per step.
// ---------------------------------------------------------------------------
__global__ __launch_bounds__(64) void qlstm_gemm(
    const float* __restrict__ x,
    const float* __restrict__ Wf, const float* __restrict__ bf,
    const float* __restrict__ Wi, const float* __restrict__ bi,
    const float* __restrict__ Wu, const float* __restrict__ bu,
    const float* __restrict__ Wo, const float* __restrict__ bo,
    const float* __restrict__ thf, const float* __restrict__ thi,
    const float* __restrict__ thu, const float* __restrict__ tho,
    float* __restrict__ Z, long long rows, int B, int D)
{
  __shared__ float tile[64][36];
  const long long base = (long long)blockIdx.x * 64;
  const int tid = threadIdx.x;  // 0..63
  const long long r = base + tid;
  const bool valid = r < rows;
  const int ldw = D + 4;
  const float* Ws[4] = {Wf, Wi, Wu, Wo};
  const float* bs[4] = {bf, bi, bu, bo};
  const float* ts[4] = {thf, thi, thu, tho};

  float acc[12];
#pragma unroll
  for (int g = 0; g < 4; ++g) {
    acc[g * 3 + 0] = bs[g][0] + ts[g][0];  // theta0 folded
    acc[g * 3 + 1] = bs[g][1];
    acc[g * 3 + 2] = bs[g][3] + ts[g][3];  // theta3 folded
  }

  const int nkc = D >> 5;  // D multiple of 32 (D=128)
  for (int kc = 0; kc < nkc; ++kc) {
    // stage 64 rows x 32 cols, coalesced (8 rows of 128B per instruction)
#pragma unroll
    for (int i = 0; i < 8; ++i) {
      int f = i * 64 + tid;
      int row = f >> 3, col = (f & 7) * 4;
      long long gr = base + row;
      if (gr < rows) {
        float4 v = *(const float4*)(x + gr * (long long)D + kc * 32 + col);
        *(float4*)&tile[row][col] = v;
      }
    }
    __syncthreads();  // 1-wave workgroup: near-free
    if (valid) {
#pragma unroll
      for (int k = 0; k < 32; k += 4) {
        float4 xv = *(float4*)&tile[tid][k];
#pragma unroll
        for (int g = 0; g < 4; ++g) {
#pragma unroll
          for (int jj = 0; jj < 3; ++jj) {
            int row2 = (jj == 2) ? 3 : jj;
            const float* wp = Ws[g] + row2 * ldw + kc * 32 + k;  // uniform -> s_load
            acc[g * 3 + jj] += xv.x * wp[0] + xv.y * wp[1] + xv.z * wp[2] + xv.w * wp[3];
          }
        }
      }
    }
    __syncthreads();
  }

  if (valid) {
    float* zp = Z + r * 16;  // [t][b][gate][4] layout, 64B per row
#pragma unroll
    for (int g = 0; g < 4; ++g) {
      *(float4*)(zp + g * 4) =
          make_float4(acc[g * 3 + 0], acc[g * 3 + 1], acc[g * 3 + 2], 0.f);
    }
  }
}

// ---------------------------------------------------------------------------
// Kernel 2: scan with 4 lanes per batch element (lane q = gate q; after the
// 4x4 quad transpose lane q = component q). Cross-lane via DPP quad_perm.
// Z layout [t][b][g][4]: ONE aligned float4 load per step per lane (was 3
// plane-scattered dwords -> 3x fewer vm ops, 1 address stream). Depth-8
// named prefetch covers L3/HBM latency (8 outstanding loads only).
// ---------------------------------------------------------------------------
__global__ __launch_bounds__(64) void qlstm_scan4(
    const float* __restrict__ Z,
    const float* __restrict__ Wf, const float* __restrict__ Wi,
    const float* __restrict__ Wu, const float* __restrict__ Wo,
    const float* __restrict__ thf, const float* __restrict__ thi,
    const float* __restrict__ thu, const float* __restrict__ tho,
    float* __restrict__ out, int T, int B, int D)
{
  const int gid = blockIdx.x * 64 + threadIdx.x;
  const int b = gid >> 2, q = gid & 3;
  if (b >= B) return;

  const float* Wg = (q == 0) ? Wf : (q == 1) ? Wi : (q == 2) ? Wu : Wo;
  const float* th = (q == 0) ? thf : (q == 1) ? thi : (q == 2) ? thu : tho;
  const int ldw = D + 4;
  const float ct1 = fast_cos(th[1]);  // cos(theta1) of this lane's gate
  const float m2c = fast_cos(th[2]);  // cos(theta2) of this lane's gate

  // wh[jj][d] pairs with h from lane q^d (component q^d): XOR-permuted load.
  float wh[3][4];
#pragma unroll
  for (int jj = 0; jj < 3; ++jj) {
    int row = (jj == 2) ? 3 : jj;
#pragma unroll
    for (int d = 0; d < 4; ++d)
      wh[jj][d] = Wg[row * ldw + D + (q ^ d)];
  }
  const bool e0 = ((q & 1) == 0);
  const bool e1 = ((q & 2) == 0);

  float h = 0.f, c = 0.f;  // this lane holds component q of h and c

  const float* Zg = Z + (size_t)gid * 4;  // lane's float4 slot within a t-slab
  const size_t tstr = (size_t)16 * B;     // floats per time step ([b][g][4])
  const size_t pstr = (size_t)4 * B;      // out floats per time step
  float* hx  = out + (size_t)T * B * 4;
  float* cxp = hx + (size_t)B * 4;

  auto ld1 = [&](int t) -> float4 {
    return *(const float4*)(Zg + (size_t)t * tstr);
  };

  auto step = [&](float4 zv, int t) {
    float z0 = zv.x, z1 = zv.y, z2 = zv.z;
    // gather all 4 h components (h from lane q^d)
    float h1 = dppf<QP_XOR1>(h);
    float h2 = dppf<QP_XOR2>(h);
    float h3 = dppf<QP_XOR3>(h);
    float a0 = fmaf(wh[0][0], h, fmaf(wh[0][1], h1, fmaf(wh[0][2], h2, fmaf(wh[0][3], h3, z0))));
    float a1 = fmaf(wh[1][0], h, fmaf(wh[1][1], h1, fmaf(wh[1][2], h2, fmaf(wh[1][3], h3, z1))));
    float a2 = fmaf(wh[2][0], h, fmaf(wh[2][1], h1, fmaf(wh[2][2], h2, fmaf(wh[2][3], h3, z2))));
    // this lane's gate: wire measurements
    float m0 = fast_cos(a0);
    float m1 = ct1 * fast_cos(a1);
    float m3 = fast_cos(a2);
    float m01 = m0 * m1, m23 = m2c * m3;
    float g0 = m1 * m23;        // <Z0> = m1 m2 m3
    float g1 = m01;             // <Z1> = m0 m1
    float g2 = m01 * m2c;       // <Z2> = m0 m1 m2
    float g3 = m01 * m23;       // <Z3> = m0 m1 m2 m3
    // 4x4 quad transpose (two XOR stages); after: w_r = gate r's component q.
    float x0 = dppf<QP_XOR1>(g0);
    float x1 = dppf<QP_XOR1>(g1);
    float x2 = dppf<QP_XOR1>(g2);
    float x3 = dppf<QP_XOR1>(g3);
    float s0 = e0 ? g0 : x1;
    float s1 = e0 ? x0 : g1;
    float s2 = e0 ? g2 : x3;
    float s3 = e0 ? x2 : g3;
    float y0 = dppf<QP_XOR2>(s0);
    float y1 = dppf<QP_XOR2>(s1);
    float y2 = dppf<QP_XOR2>(s2);
    float y3 = dppf<QP_XOR2>(s3);
    float wf_ = e1 ? s0 : y2;
    float wi_ = e1 ? s1 : y3;
    float wu_ = e1 ? y0 : s2;
    float wo_ = e1 ? y1 : s3;
    // gates (|input| <= 1: products of cosines)
    float fg = sigmoid_poly(wf_);
    float ig = sigmoid_poly(wi_);
    float ug = tanh_pade(wu_);
    float og = sigmoid_poly(wo_);
    c = fmaf(fg, c, ig * ug);
    h = og * tanh_pade(c);
    out[(size_t)t * pstr + gid] = h;
  };

  // depth-8 named prefetch pipeline (rule #20: no runtime-indexed arrays)
  float4 A, Bv, C, Dv, E, F, G, H;
  if (T > 0) A  = ld1(0);
  if (T > 1) Bv = ld1(1);
  if (T > 2) C  = ld1(2);
  if (T > 3) Dv = ld1(3);
  if (T > 4) E  = ld1(4);
  if (T > 5) F  = ld1(5);
  if (T > 6) G  = ld1(6);
  if (T > 7) H  = ld1(7);

  int T8 = T & ~7;
  for (int t = 0; t < T8; t += 8) {
    { float4 zv = A;  if (t + 8  < T) A  = ld1(t + 8);  step(zv, t);     }
    { float4 zv = Bv; if (t + 9  < T) Bv = ld1(t + 9);  step(zv, t + 1); }
    { float4 zv = C;  if (t + 10 < T) C  = ld1(t + 10); step(zv, t + 2); }
    { float4 zv = Dv; if (t + 11 < T) Dv = ld1(t + 11); step(zv, t + 3); }
    { float4 zv = E;  if (t + 12 < T) E  = ld1(t + 12); step(zv, t + 4); }
    { float4 zv = F;  if (t + 13 < T) F  = ld1(t + 13); step(zv, t + 5); }
    { float4 zv = G;  if (t + 14 < T) G  = ld1(t + 14); step(zv, t + 6); }
    { float4 zv = H;  if (t + 15 < T) H  = ld1(t + 15); step(zv, t + 7); }
  }
  for (int t = T8; t < T; ++t) {
    step(ld1(t), t);
  }
  hx[gid]  = h;
  cxp[gid] = c;
}

// ---------------------------------------------------------------------------
// Fallback (only if workspace can't hold Z): fused, slow but correct.
// ---------------------------------------------------------------------------
struct GK {
  float wh[4][3][4];
  float ct1[4];
  float m2c[4];
};

__device__ __forceinline__ void load_gk(GK& K,
    const float* Wf, const float* Wi, const float* Wu, const float* Wo,
    const float* thf, const float* thi, const float* thu, const float* tho,
    int D)
{
  const float* Ws[4] = {Wf, Wi, Wu, Wo};
  const float* ts[4] = {thf, thi, thu, tho};
  const int ldw = D + 4;
#pragma unroll
  for (int g = 0; g < 4; ++g) {
#pragma unroll
    for (int jj = 0; jj < 3; ++jj) {
      int row = (jj == 2) ? 3 : jj;
#pragma unroll
      for (int qq = 0; qq < 4; ++qq)
        K.wh[g][jj][qq] = Ws[g][row * ldw + D + qq];
    }
    K.ct1[g] = fast_cos(ts[g][1]);
    K.m2c[g] = fast_cos(ts[g][2]);
  }
}

__device__ __forceinline__ void qlstm_step_sc(const float a[12], const GK& K,
                                              float h[4], float c[4])
{
  float gv[4][4];
#pragma unroll
  for (int g = 0; g < 4; ++g) {
    float m0 = fast_cos(a[g * 3 + 0]);
    float m1 = K.ct1[g] * fast_cos(a[g * 3 + 1]);
    float m3 = fast_cos(a[g * 3 + 2]);
    float m01 = m0 * m1;
    float m23 = K.m2c[g] * m3;
    gv[g][0] = m1 * m23;
    gv[g][1] = m01;
    gv[g][2] = m01 * K.m2c[g];
    gv[g][3] = m01 * m23;
  }
#pragma unroll
  for (int qq = 0; qq < 4; ++qq) {
    float fg = fast_sigmoid(gv[0][qq]);
    float ig = fast_sigmoid(gv[1][qq]);
    float ug = fast_tanh(gv[2][qq]);
    float og = fast_sigmoid(gv[3][qq]);
    c[qq] = fg * c[qq] + ig * ug;
    h[qq] = og * fast_tanh(c[qq]);
  }
}

__global__ __launch_bounds__(256) void qlstm_fused(
    const float* __restrict__ x,
    const float* __restrict__ Wf, const float* __restrict__ bf,
    const float* __restrict__ Wi, const float* __restrict__ bi,
    const float* __restrict__ Wu, const float* __restrict__ bu,
    const float* __restrict__ Wo, const float* __restrict__ bo,
    const float* __restrict__ thf, const float* __restrict__ thi,
    const float* __restrict__ thu, const float* __restrict__ tho,
    float* __restrict__ out, int T, int B, int D)
{
  int b = blockIdx.x * 256 + threadIdx.x;
  if (b >= B) return;
  GK K;
  load_gk(K, Wf, Wi, Wu, Wo, thf, thi, thu, tho, D);
  const float* Ws[4] = {Wf, Wi, Wu, Wo};
  const float* bs[4] = {bf, bi, bu, bo};
  const float* ts[4] = {thf, thi, thu, tho};
  const int ldw = D + 4;

  float base[12];
#pragma unroll
  for (int g = 0; g < 4; ++g) {
    base[g * 3 + 0] = bs[g][0] + ts[g][0];
    base[g * 3 + 1] = bs[g][1];
    base[g * 3 + 2] = bs[g][3] + ts[g][3];
  }

  float h[4] = {0.f, 0.f, 0.f, 0.f};
  float c[4] = {0.f, 0.f, 0.f, 0.f};
  float* hx  = out + (size_t)T * B * 4;
  float* cxp = hx + (size_t)B * 4;

  for (int t = 0; t < T; ++t) {
    float a[12];
#pragma unroll
    for (int j = 0; j < 12; ++j) a[j] = base[j];
    const float* xp = x + ((size_t)t * B + b) * D;
    for (int k = 0; k < D; k += 4) {
      float4 xv = *(const float4*)(xp + k);
#pragma unroll
      for (int g = 0; g < 4; ++g) {
        const float* W = Ws[g];
#pragma unroll
        for (int jj = 0; jj < 3; ++jj) {
          int row = (jj == 2) ? 3 : jj;
          const float* wp = W + row * ldw + k;
          a[g * 3 + jj] += xv.x * wp[0] + xv.y * wp[1] + xv.z * wp[2] + xv.w * wp[3];
        }
      }
    }
#pragma unroll
    for (int g = 0; g < 4; ++g) {
#pragma unroll
      for (int jj = 0; jj < 3; ++jj) {
        a[g * 3 + jj] += K.wh[g][jj][0] * h[0] + K.wh[g][jj][1] * h[1]
                       + K.wh[g][jj][2] * h[2] + K.wh[g][jj][3] * h[3];
      }
    }
    qlstm_step_sc(a, K, h, c);
    *(float4*)(out + ((size_t)t * B + b) * 4) = make_float4(h[0], h[1], h[2], h[3]);
  }
  *(float4*)(hx + (size_t)b * 4)  = make_float4(h[0], h[1], h[2], h[3]);
  *(float4*)(cxp + (size_t)b * 4) = make_float4(c[0], c[1], c[2], c[3]);
}

// ---------------------------------------------------------------------------
extern "C" void kernel_launch(void* const* d_in, const int* in_sizes, int n_in,
                              void* d_out, int out_size, void* d_ws, size_t ws_size,
                              hipStream_t stream)
{
  const float* x   = (const float*)d_in[0];
  const float* Wf  = (const float*)d_in[1];
  const float* bf  = (const float*)d_in[2];
  const float* Wi  = (const float*)d_in[3];
  const float* bi  = (const float*)d_in[4];
  const float* Wu  = (const float*)d_in[5];
  const float* bu  = (const float*)d_in[6];
  const float* Wo  = (const float*)d_in[7];
  const float* bo  = (const float*)d_in[8];
  const float* thf = (const float*)d_in[9];
  const float* thi = (const float*)d_in[10];
  const float* thu = (const float*)d_in[11];
  const float* tho = (const float*)d_in[12];

  int DH = in_sizes[1] / 4;                 // D + H (H = 4)
  int D  = DH - 4;                          // 128
  long long TB = (long long)in_sizes[0] / D;          // T*B
  int B = (int)(((long long)out_size - 4 * TB) / 8);  // out = 4*T*B + 8*B
  int T = (int)(TB / B);

  size_t zbytes = (size_t)TB * 16 * sizeof(float);
  if (ws_size >= zbytes && (D & 31) == 0) {
    float* Z = (float*)d_ws;
    int gblocks = (int)((TB + 63) / 64);
    qlstm_gemm<<<gblocks, 64, 0, stream>>>(x, Wf, bf, Wi, bi, Wu, bu, Wo, bo,
                                           thf, thi, thu, tho, Z, TB, B, D);
    int sthreads = B * 4;
    qlstm_scan4<<<(sthreads + 63) / 64, 64, 0, stream>>>(Z, Wf, Wi, Wu, Wo,
                                                         thf, thi, thu, tho,
                                                         (float*)d_out, T, B, D);
  } else {
    qlstm_fused<<<(B + 255) / 256, 256, 0, stream>>>(x, Wf, bf, Wi, bi, Wu, bu, Wo, bo,
                                                     thf, thi, thu, tho,
                                                     (float*)d_out, T, B, D);
  }
}